// Round 2
// baseline (423.513 us; speedup 1.0000x reference)
//
#include <hip/hip_runtime.h>
#include <cstddef>

typedef unsigned short u16;
typedef __bf16 bf16x8 __attribute__((ext_vector_type(8)));
typedef float f32x4 __attribute__((ext_vector_type(4)));
typedef u16 u16x8 __attribute__((ext_vector_type(8)));

__device__ __forceinline__ u16 f2bf(float f) {
  unsigned u = __builtin_bit_cast(unsigned, f);
  u += 0x7fffu + ((u >> 16) & 1u);   // round-to-nearest-even
  return (u16)(u >> 16);
}
__device__ __forceinline__ float bf2f(u16 h) {
  return __builtin_bit_cast(float, ((unsigned)h) << 16);
}
__device__ __forceinline__ void gld_lds16(const void* g, void* l) {
  __builtin_amdgcn_global_load_lds((const __attribute__((address_space(1))) void*)g,
                                   (__attribute__((address_space(3))) void*)l, 16, 0, 0);
}
__device__ __forceinline__ int swz4(int r) { return (r ^ (r >> 2)) & 3; }

// ---------------- f32 -> bf16 conversion, 8 elems/thread ----------------
__global__ __launch_bounds__(256) void cvt_kernel(const float* __restrict__ in,
                                                  u16* __restrict__ out, int n) {
  int i = (blockIdx.x * 256 + threadIdx.x) * 8;
  if (i >= n) return;
  f32x4 a = *(const f32x4*)(in + i);
  f32x4 b = *(const f32x4*)(in + i + 4);
  u16x8 o;
  o[0] = f2bf(a[0]); o[1] = f2bf(a[1]); o[2] = f2bf(a[2]); o[3] = f2bf(a[3]);
  o[4] = f2bf(b[0]); o[5] = f2bf(b[1]); o[6] = f2bf(b[2]); o[7] = f2bf(b[3]);
  *(u16x8*)(out + i) = o;
}

// =====================================================================
// 8-phase 256xBN B^T GEMM (T2 swizzle + T3/T4 counted-vmcnt + T5 setprio)
// C[m][n] = sum_k A[m][k]*B[n][k].  512 threads, 8 waves (2M x 4N).
// K-tile = 64, split into two K-halves of 32 -> half-tiles A_k0,B_k0,A_k1,B_k1.
// LDS ring: A slots [2buf][2ksub] 16KB each, B slots [2buf][2ksub] BHB each.
// Issue lead = 7 half-tiles; vmcnt(4+BLOADS) before tile-boundary barrier.
// EPI: 3 = scores (bf16, *scale, C[z][gm*N+gn])
//      4 = PV     (bf16, oflat[z][gm>>3][ (gm&7)*512 + gn ])
// =====================================================================
template<int BN, int EPI>
__global__ __launch_bounds__(512, 2) void gemm8(
    const u16* __restrict__ A, const u16* __restrict__ B, u16* __restrict__ C,
    int N, int K, float scale, long bsA, long bsB, long bsC)
{
  constexpr int BM = 256;
  constexpr int WN = BN / 4;           // per-wave N cols
  constexpr int FN = WN / 16;          // 4 (BN=256) or 2 (BN=128)
  constexpr int AHB = 16384;           // A half-tile bytes (256 rows x 32 elems x 2B)
  constexpr int BHB = BN * 32 * 2;     // B half-tile bytes
  constexpr int BLOADS = BHB / 8192;   // gld_lds per thread per B half (2 or 1)
  constexpr int VN = 4 + BLOADS;       // steady-state vmcnt (3 half-tiles in flight)

  __shared__ char smem[4 * AHB + 4 * BHB];

  const int tid = threadIdx.x, lid = tid & 63, wid = tid >> 6;
  const int wm = wid >> 2, wn = wid & 3;
  const int m0 = blockIdx.y * BM, n0 = blockIdx.x * BN, z = blockIdx.z;
  A += (size_t)z * bsA;
  B += (size_t)z * bsB;
  const int NT = K >> 6;

  // per-lane ds_read byte offsets (within a half-tile slot), swizzled
  int offA[8], offB[FN];
#pragma unroll
  for (int cf = 0; cf < 2; ++cf)
#pragma unroll
    for (int f = 0; f < 4; ++f) {
      int row = wm * 128 + cf * 64 + f * 16 + (lid & 15);
      offA[cf * 4 + f] = row * 64 + (((lid >> 4) ^ swz4(row)) * 16);
    }
#pragma unroll
  for (int f = 0; f < FN; ++f) {
    int row = wn * WN + f * 16 + (lid & 15);
    offB[f] = row * 64 + (((lid >> 4) ^ swz4(row)) * 16);
  }

  // stage one half-tile (index j): linear LDS dest, inverse-swizzled global src
  auto stage = [&](int j) {
    const int ts = j >> 2, tp = j & 3, ks = tp >> 1;
    if (!(tp & 1)) {                    // A half
      char* dst = smem + (ts & 1) * (2 * AHB) + ks * AHB;
      const u16* sa = A + (size_t)ts * 64 + ks * 32;
#pragma unroll
      for (int l = 0; l < 2; ++l) {
        int r = l * 128 + (tid >> 2);
        int c = (tid & 3) ^ swz4(r);
        gld_lds16(sa + (size_t)(m0 + r) * K + c * 8, dst + l * 8192 + tid * 16);
      }
    } else {                            // B half
      char* dst = smem + 4 * AHB + (ts & 1) * (2 * BHB) + ks * BHB;
      const u16* sb = B + (size_t)ts * 64 + ks * 32;
#pragma unroll
      for (int l = 0; l < BLOADS; ++l) {
        int r = l * 128 + (tid >> 2);
        int c = (tid & 3) ^ swz4(r);
        gld_lds16(sb + (size_t)(n0 + r) * K + c * 8, dst + l * 8192 + tid * 16);
      }
    }
  };

  f32x4 acc[8][FN];
#pragma unroll
  for (int i = 0; i < 8; ++i)
#pragma unroll
    for (int j = 0; j < FN; ++j) acc[i][j] = 0.0f;

  // prologue: tile0 (4 halves) + tile1 first 3 halves; wait tile0 landed
  for (int j = 0; j < 7 && j < 4 * NT; ++j) stage(j);
  if constexpr (BLOADS == 2) asm volatile("s_waitcnt vmcnt(6)" ::: "memory");
  else                       asm volatile("s_waitcnt vmcnt(5)" ::: "memory");
  __builtin_amdgcn_s_barrier();

  int h = 7;
  for (int t = 0; t < NT; ++t) {
    const int ab0 = (t & 1) * (2 * AHB);
    const int bb0 = 4 * AHB + (t & 1) * (2 * BHB);
#pragma unroll
    for (int p = 0; p < 4; ++p) {       // phase = (ksub, chalf)
      const int ks = p >> 1, cf = p & 1;
      const char* ab = smem + ab0 + ks * AHB;
      const char* bb = smem + bb0 + ks * BHB;
      bf16x8 ar[4], br[FN];
#pragma unroll
      for (int f = 0; f < 4; ++f) ar[f] = *(const bf16x8*)(ab + offA[cf * 4 + f]);
#pragma unroll
      for (int f = 0; f < FN; ++f) br[f] = *(const bf16x8*)(bb + offB[f]);
      if (h < 4 * NT) stage(h);
      ++h;
      __builtin_amdgcn_s_barrier();
      __builtin_amdgcn_s_setprio(1);
#pragma unroll
      for (int f = 0; f < 4; ++f)
#pragma unroll
        for (int n = 0; n < FN; ++n)
          acc[cf * 4 + f][n] =
              __builtin_amdgcn_mfma_f32_16x16x32_bf16(ar[f], br[n], acc[cf * 4 + f][n], 0, 0, 0);
      __builtin_amdgcn_s_setprio(0);
      if (p == 3 && t < NT - 1) {       // guard next tile's data (counted, never 0 mid-loop)
        if (t == NT - 2) asm volatile("s_waitcnt vmcnt(0)" ::: "memory");
        else if constexpr (BLOADS == 2) asm volatile("s_waitcnt vmcnt(6)" ::: "memory");
        else                            asm volatile("s_waitcnt vmcnt(5)" ::: "memory");
      }
      __builtin_amdgcn_s_barrier();
    }
  }

  // epilogue
  const size_t cb = (size_t)z * bsC;
#pragma unroll
  for (int mf = 0; mf < 8; ++mf)
#pragma unroll
    for (int nf = 0; nf < FN; ++nf)
#pragma unroll
      for (int r = 0; r < 4; ++r) {
        int gm = m0 + wm * 128 + mf * 16 + ((lid >> 4) << 2) + r;
        int gn = n0 + wn * WN + nf * 16 + (lid & 15);
        float v = acc[mf][nf][r];
        if constexpr (EPI == 3) {
          C[cb + (size_t)gm * N + gn] = f2bf(v * scale);
        } else {
          C[cb + (size_t)(gm >> 3) * 4096 + (size_t)(gm & 7) * 512 + gn] = f2bf(v);
        }
      }
}

// ---------------- generic B^T GEMM (projections / final), 128-tile ----------------
template<int BM, int BN, int EPI>
__global__ __launch_bounds__(256) void gemm_bt(
    const u16* __restrict__ A, const u16* __restrict__ B, void* __restrict__ Cv,
    const float* __restrict__ bias, int M, int N, int K, float scale,
    long bsA, long bsB, long bsC)
{
  constexpr int BK  = 64;
  constexpr int WMT = BM / 2, WNT = BN / 2;
  constexpr int FM  = BM / 32, FN = BN / 32;
  constexpr int STAGE = (BM + BN) * BK * 2;
  constexpr int EPIB  = (EPI == 2) ? BM * (BN + 1) * 2 : 0;
  __shared__ alignas(16) char smem[(STAGE > EPIB) ? STAGE : EPIB];
  u16* As = (u16*)smem;
  u16* Bs = As + BM * BK;

  const int tid = threadIdx.x;
  const int lid = tid & 63, wid = tid >> 6;
  const int m0 = blockIdx.y * BM, n0 = blockIdx.x * BN;
  const int z  = blockIdx.z;
  A += (size_t)z * bsA;
  B += (size_t)z * bsB;
  (void)M;

  const int wm = wid >> 1, wn = wid & 1;

  f32x4 acc[FM][FN];
#pragma unroll
  for (int i = 0; i < FM; ++i)
#pragma unroll
    for (int j = 0; j < FN; ++j) acc[i][j] = 0.0f;

  const int rA = lid >> 3;
  const int ke = (lid & 7) * 8;

  const int nK = K / BK;
  for (int kt = 0; kt < nK; ++kt) {
    const int k0 = kt * BK;
#pragma unroll
    for (int c = 0; c < BM / 32; ++c) {
      int chunk = wid * (BM / 32) + c;
      const u16* src = A + (size_t)(m0 + chunk * 8 + rA) * K + k0 + ke;
      gld_lds16(src, (char*)As + chunk * 1024);
    }
#pragma unroll
    for (int c = 0; c < BN / 32; ++c) {
      int chunk = wid * (BN / 32) + c;
      const u16* src = B + (size_t)(n0 + chunk * 8 + rA) * K + k0 + ke;
      gld_lds16(src, (char*)Bs + chunk * 1024);
    }
    __syncthreads();

#pragma unroll
    for (int kc = 0; kc < 2; ++kc) {
      bf16x8 af[FM], bfv[FN];
      const int kb = kc * 32 + (lid >> 4) * 8;
#pragma unroll
      for (int i = 0; i < FM; ++i)
        af[i] = *(const bf16x8*)&As[(wm * WMT + i * 16 + (lid & 15)) * BK + kb];
#pragma unroll
      for (int j = 0; j < FN; ++j)
        bfv[j] = *(const bf16x8*)&Bs[(wn * WNT + j * 16 + (lid & 15)) * BK + kb];
#pragma unroll
      for (int i = 0; i < FM; ++i)
#pragma unroll
        for (int j = 0; j < FN; ++j)
          acc[i][j] = __builtin_amdgcn_mfma_f32_16x16x32_bf16(af[i], bfv[j], acc[i][j], 0, 0, 0);
    }
    __syncthreads();
  }

#pragma unroll
  for (int i = 0; i < FM; ++i) {
#pragma unroll
    for (int j = 0; j < FN; ++j) {
#pragma unroll
      for (int r = 0; r < 4; ++r) {
        int lm = wm * WMT + i * 16 + ((lid >> 4) << 2) + r;
        int ln = wn * WNT + j * 16 + (lid & 15);
        int gm = m0 + lm, gn = n0 + ln;
        float val = acc[i][j][r];
        if constexpr (EPI == 0 || EPI == 1 || EPI == 2) val += bias[gn];
        if constexpr (EPI == 3) val *= scale;

        if constexpr (EPI == 0) {
          int b = gm >> 9, s = gm & 511, hh = gn >> 9, d2 = gn & 511;
          ((u16*)Cv)[(size_t)b * 2097152 + (size_t)((s << 3) + hh) * 512 + d2] = f2bf(val);
        } else if constexpr (EPI == 1) {
          int b = gm >> 9, s = gm & 511, hh = gn >> 9, d2 = gn & 511;
          ((u16*)Cv)[(size_t)b * 2097152 + (size_t)((hh << 9) + s) * 512 + d2] = f2bf(val);
        } else if constexpr (EPI == 2) {
          u16* E = (u16*)smem;
          E[lm * (BN + 1) + ln] = f2bf(val);
        } else if constexpr (EPI == 3) {
          u16* C = (u16*)Cv + (size_t)z * bsC;
          C[(size_t)gm * N + gn] = f2bf(val);
        } else if constexpr (EPI == 4) {
          u16* C = (u16*)Cv + (size_t)z * bsC;
          C[(size_t)(gm >> 3) * 4096 + (size_t)(gm & 7) * 512 + gn] = f2bf(val);
        } else {
          float* C = (float*)Cv;
          C[(size_t)gm * N + gn] = val + bias[gn];
        }
      }
    }
  }

  if constexpr (EPI == 2) {
    static_assert(BM == 128 && BN == 128, "V-proj epilogue assumes 128x128 tile");
    __syncthreads();
    int b = m0 >> 9, s0 = m0 & 511, hh = n0 >> 9, d20 = n0 & 511;
    u16* E = (u16*)smem;
    int c  = tid >> 1;
    int r0 = (tid & 1) * 64;
    u16* dst = (u16*)Cv + (size_t)b * 2097152 + (size_t)(d20 + c) * 4096 + (hh << 9) + s0 + r0;
#pragma unroll
    for (int i = 0; i < 64; i += 8) {
      u16x8 p;
#pragma unroll
      for (int jj = 0; jj < 8; ++jj) p[jj] = E[(r0 + i + jj) * (BN + 1) + c];
      *(u16x8*)(dst + i) = p;
    }
  }
}

// ---------------- row softmax over 4096 bf16, in place ----------------
__global__ __launch_bounds__(256) void softmax_kernel(u16* __restrict__ S) {
  const size_t row = blockIdx.x;
  u16* p = S + row * 4096;
  const int t = threadIdx.x;
  float v[16];
#pragma unroll
  for (int i = 0; i < 2; ++i) {
    u16x8 x = *(const u16x8*)(p + i * 2048 + t * 8);
#pragma unroll
    for (int j = 0; j < 8; ++j) v[i * 8 + j] = bf2f(x[j]);
  }
  float m = v[0];
#pragma unroll
  for (int i = 1; i < 16; ++i) m = fmaxf(m, v[i]);
#pragma unroll
  for (int o = 32; o; o >>= 1) m = fmaxf(m, __shfl_xor(m, o));
  __shared__ float red[8];
  int w = t >> 6;
  if ((t & 63) == 0) red[w] = m;
  __syncthreads();
  m = fmaxf(fmaxf(red[0], red[1]), fmaxf(red[2], red[3]));
  float sum = 0.0f;
#pragma unroll
  for (int i = 0; i < 16; ++i) { v[i] = __expf(v[i] - m); sum += v[i]; }
#pragma unroll
  for (int o = 32; o; o >>= 1) sum += __shfl_xor(sum, o);
  __syncthreads();
  if ((t & 63) == 0) red[4 + w] = sum;
  __syncthreads();
  sum = red[4] + red[5] + red[6] + red[7];
  float inv = 1.0f / sum;
#pragma unroll
  for (int i = 0; i < 2; ++i) {
    u16x8 x;
#pragma unroll
    for (int j = 0; j < 8; ++j) x[j] = f2bf(v[i * 8 + j] * inv);
    *(u16x8*)(p + i * 2048 + t * 8) = x;
  }
}

// ---------------------------------------------------------------------------
extern "C" void kernel_launch(void* const* d_in, const int* in_sizes, int n_in,
                              void* d_out, int out_size, void* d_ws, size_t ws_size,
                              hipStream_t stream) {
  (void)in_sizes; (void)n_in; (void)out_size;
  const float* q_f  = (const float*)d_in[0];
  const float* k_f  = (const float*)d_in[1];
  const float* v_f  = (const float*)d_in[2];
  const float* wq_b = (const float*)d_in[4];
  const float* wk_b = (const float*)d_in[6];
  const float* wv_b = (const float*)d_in[8];
  const float* ou_b = (const float*)d_in[10];
  float* out = (float*)d_out;

  char* ws = (char*)d_ws;
  u16* q_bf  = (u16*)(ws + 0);
  u16* k_bf  = (u16*)(ws + 2097152);
  u16* v_bf  = (u16*)(ws + 4194304);
  u16* wA_q  = (u16*)(ws + 6291456);    // bf16(wk_w)  (reference swaps wk<->wq)
  u16* wA_k  = (u16*)(ws + 10485760);   // bf16(wq_w)
  u16* wA_v  = (u16*)(ws + 14680064);   // bf16(wv_w)
  u16* ow_bf = (u16*)(ws + 18874368);   // bf16(out_w)
  u16* qp    = (u16*)(ws + 23068672);   // (4, 4096, 512) bf16, l = s*8+h
  u16* kp    = (u16*)(ws + 39845888);   // (4, 4096, 512) bf16, l' = h*512+s
  u16* vpt   = (u16*)(ws + 56623104);   // (4, 512, 4096) bf16, [d2][l']
  u16* oflat = (u16*)(ws + 73400320);   // (4, 512, 4096) bf16 (= o reshaped)
  u16* sc    = (u16*)(ws + 90177536);   // scores/attn bf16
  bool full = ws_size >= (size_t)90177536 + 134217728;

  // f32 -> bf16 converts
  cvt_kernel<<<512,  256, 0, stream>>>(q_f, q_bf, 1048576);
  cvt_kernel<<<512,  256, 0, stream>>>(k_f, k_bf, 1048576);
  cvt_kernel<<<512,  256, 0, stream>>>(v_f, v_bf, 1048576);
  cvt_kernel<<<1024, 256, 0, stream>>>((const float*)d_in[5], wA_q, 2097152);
  cvt_kernel<<<1024, 256, 0, stream>>>((const float*)d_in[3], wA_k, 2097152);
  cvt_kernel<<<1024, 256, 0, stream>>>((const float*)d_in[7], wA_v, 2097152);
  cvt_kernel<<<1024, 256, 0, stream>>>((const float*)d_in[9], ow_bf, 2097152);

  // projections (note reference swap: qp uses wk, kp uses wq)
  gemm_bt<128,128,0><<<dim3(32,16,1), 256, 0, stream>>>(q_bf, wA_q, qp,  wk_b, 2048,4096,512, 1.f, 0,0,0);
  gemm_bt<128,128,1><<<dim3(32,16,1), 256, 0, stream>>>(k_bf, wA_k, kp,  wq_b, 2048,4096,512, 1.f, 0,0,0);
  gemm_bt<128,128,2><<<dim3(32,16,1), 256, 0, stream>>>(v_bf, wA_v, vpt, wv_b, 2048,4096,512, 1.f, 0,0,0);

  const float scl = 0.04419417382415922f;  // 1/sqrt(512)
  if (full) {
    gemm8<256,3><<<dim3(16,16,4), 512, 0, stream>>>(qp, kp, sc, 4096, 512, scl,
                                                    2097152, 2097152, 16777216);
    softmax_kernel<<<16384, 256, 0, stream>>>(sc);
    gemm8<128,4><<<dim3(4,16,4), 512, 0, stream>>>(sc, vpt, oflat, 512, 4096, 1.f,
                                                   16777216, 2097152, 2097152);
  } else {
    for (int b = 0; b < 4; ++b) {
      gemm8<256,3><<<dim3(16,16,1), 512, 0, stream>>>(qp + b*2097152, kp + b*2097152, sc,
                                                      4096, 512, scl, 0,0,0);
      softmax_kernel<<<4096, 256, 0, stream>>>(sc);
      gemm8<128,4><<<dim3(4,16,1), 512, 0, stream>>>(sc, vpt + b*2097152, oflat + b*2097152,
                                                     512, 4096, 1.f, 0,0,0);
    }
  }
  // final projection, f32 output
  gemm_bt<64,64,5><<<dim3(8,32,1), 256, 0, stream>>>(oflat, ow_bf, out, ou_b, 2048,512,4096, 1.f, 0,0,0);
}

// Round 3
// 352.026 us; speedup vs baseline: 1.2031x; 1.2031x over previous
//
#include <hip/hip_runtime.h>
#include <cstddef>

typedef unsigned short u16;
typedef __bf16 bf16x8 __attribute__((ext_vector_type(8)));
typedef float f32x4 __attribute__((ext_vector_type(4)));
typedef u16 u16x8 __attribute__((ext_vector_type(8)));

__device__ __forceinline__ u16 f2bf(float f) {
  unsigned u = __builtin_bit_cast(unsigned, f);
  u += 0x7fffu + ((u >> 16) & 1u);   // round-to-nearest-even
  return (u16)(u >> 16);
}
__device__ __forceinline__ float bf2f(u16 h) {
  return __builtin_bit_cast(float, ((unsigned)h) << 16);
}
__device__ __forceinline__ void gld_lds16(const void* g, void* l) {
  __builtin_amdgcn_global_load_lds((const __attribute__((address_space(1))) void*)g,
                                   (__attribute__((address_space(3))) void*)l, 16, 0, 0);
}
__device__ __forceinline__ int swz4(int r) { return (r ^ (r >> 2)) & 3; }

// ---------------- f32 -> bf16 conversion, 8 elems/thread ----------------
__global__ __launch_bounds__(256) void cvt_kernel(const float* __restrict__ in,
                                                  u16* __restrict__ out, int n) {
  int i = (blockIdx.x * 256 + threadIdx.x) * 8;
  if (i >= n) return;
  f32x4 a = *(const f32x4*)(in + i);
  f32x4 b = *(const f32x4*)(in + i + 4);
  u16x8 o;
  o[0] = f2bf(a[0]); o[1] = f2bf(a[1]); o[2] = f2bf(a[2]); o[3] = f2bf(a[3]);
  o[4] = f2bf(b[0]); o[5] = f2bf(b[1]); o[6] = f2bf(b[2]); o[7] = f2bf(b[3]);
  *(u16x8*)(out + i) = o;
}

// =====================================================================
// 8-phase 256xBN B^T GEMM (T2 swizzle + T3/T4 counted-vmcnt + T5 setprio)
// C[m][n] = sum_k A[m][k]*B[n][k].  512 threads, 8 waves (2M x 4N).
// XCD-aware bijective block swizzle: x-blocks sharing an A-panel co-XCD.
// EPI: 3 = scores (bf16, *scale)                  [fallback path]
//      4 = PV -> oflat                            [fallback path]
//      6 = scores -> P=exp(s*scale) bf16 + row-sum L (atomicAdd)
//      7 = PV -> oflat, divided by L[row]
// =====================================================================
template<int BN, int EPI>
__global__ __launch_bounds__(512, 2) void gemm8(
    const u16* __restrict__ A, const u16* __restrict__ B, u16* __restrict__ C,
    float* __restrict__ Lbuf, int N, int K, float scale,
    long bsA, long bsB, long bsC)
{
  constexpr int BM = 256;
  constexpr int WN = BN / 4;           // per-wave N cols
  constexpr int FN = WN / 16;          // 4 (BN=256) or 2 (BN=128)
  constexpr int AHB = 16384;           // A half-tile bytes (256 rows x 32 elems x 2B)
  constexpr int BHB = BN * 32 * 2;     // B half-tile bytes
  constexpr int BLOADS = BHB / 8192;   // gld_lds per thread per B half (2 or 1)

  __shared__ char smem[4 * AHB + 4 * BHB];

  const int tid = threadIdx.x, lid = tid & 63, wid = tid >> 6;
  const int wm = wid >> 2, wn = wid & 3;

  // XCD-aware bijective swizzle: dispatch round-robins lin%8 across XCDs.
  // Map so the nx x-blocks of one (y,z) chunk get the same xcd -> shared A in L2.
  const int nx = gridDim.x, ny = gridDim.y;
  const int lin = blockIdx.x + nx * (blockIdx.y + ny * blockIdx.z);
  const int xcd = lin & 7, slot = lin >> 3;
  const int wx = slot % nx;
  const int c_ = xcd + (slot / nx) * 8;
  const int m0 = (c_ % ny) * BM, n0 = wx * BN, z = c_ / ny;

  A += (size_t)z * bsA;
  B += (size_t)z * bsB;
  const int NT = K >> 6;

  // per-lane ds_read byte offsets (within a half-tile slot), swizzled
  int offA[8], offB[FN];
#pragma unroll
  for (int cf = 0; cf < 2; ++cf)
#pragma unroll
    for (int f = 0; f < 4; ++f) {
      int row = wm * 128 + cf * 64 + f * 16 + (lid & 15);
      offA[cf * 4 + f] = row * 64 + (((lid >> 4) ^ swz4(row)) * 16);
    }
#pragma unroll
  for (int f = 0; f < FN; ++f) {
    int row = wn * WN + f * 16 + (lid & 15);
    offB[f] = row * 64 + (((lid >> 4) ^ swz4(row)) * 16);
  }

  // stage one half-tile (index j): linear LDS dest, inverse-swizzled global src
  auto stage = [&](int j) {
    const int ts = j >> 2, tp = j & 3, ks = tp >> 1;
    if (!(tp & 1)) {                    // A half
      char* dst = smem + (ts & 1) * (2 * AHB) + ks * AHB;
      const u16* sa = A + (size_t)ts * 64 + ks * 32;
#pragma unroll
      for (int l = 0; l < 2; ++l) {
        int r = l * 128 + (tid >> 2);
        int cc = (tid & 3) ^ swz4(r);
        gld_lds16(sa + (size_t)(m0 + r) * K + cc * 8, dst + l * 8192 + tid * 16);
      }
    } else {                            // B half
      char* dst = smem + 4 * AHB + (ts & 1) * (2 * BHB) + ks * BHB;
      const u16* sb = B + (size_t)ts * 64 + ks * 32;
#pragma unroll
      for (int l = 0; l < BLOADS; ++l) {
        int r = l * 128 + (tid >> 2);
        int cc = (tid & 3) ^ swz4(r);
        gld_lds16(sb + (size_t)(n0 + r) * K + cc * 8, dst + l * 8192 + tid * 16);
      }
    }
  };

  f32x4 acc[8][FN];
#pragma unroll
  for (int i = 0; i < 8; ++i)
#pragma unroll
    for (int j = 0; j < FN; ++j) acc[i][j] = 0.0f;

  // prologue: tile0 (4 halves) + tile1 first 3 halves; wait tile0 landed
  for (int j = 0; j < 7 && j < 4 * NT; ++j) stage(j);
  if constexpr (BLOADS == 2) asm volatile("s_waitcnt vmcnt(6)" ::: "memory");
  else                       asm volatile("s_waitcnt vmcnt(5)" ::: "memory");
  __builtin_amdgcn_s_barrier();

  int h = 7;
  for (int t = 0; t < NT; ++t) {
    const int ab0 = (t & 1) * (2 * AHB);
    const int bb0 = 4 * AHB + (t & 1) * (2 * BHB);
#pragma unroll
    for (int p = 0; p < 4; ++p) {       // phase = (ksub, chalf)
      const int ks = p >> 1, cf = p & 1;
      const char* ab = smem + ab0 + ks * AHB;
      const char* bb = smem + bb0 + ks * BHB;
      bf16x8 ar[4], br[FN];
#pragma unroll
      for (int f = 0; f < 4; ++f) ar[f] = *(const bf16x8*)(ab + offA[cf * 4 + f]);
#pragma unroll
      for (int f = 0; f < FN; ++f) br[f] = *(const bf16x8*)(bb + offB[f]);
      if (h < 4 * NT) stage(h);
      ++h;
      __builtin_amdgcn_s_barrier();
      __builtin_amdgcn_s_setprio(1);
#pragma unroll
      for (int f = 0; f < 4; ++f)
#pragma unroll
        for (int n = 0; n < FN; ++n)
          acc[cf * 4 + f][n] =
              __builtin_amdgcn_mfma_f32_16x16x32_bf16(ar[f], br[n], acc[cf * 4 + f][n], 0, 0, 0);
      __builtin_amdgcn_s_setprio(0);
      if (p == 3 && t < NT - 1) {       // guard next tile's data (counted, never 0 mid-loop)
        if (t == NT - 2) asm volatile("s_waitcnt vmcnt(0)" ::: "memory");
        else if constexpr (BLOADS == 2) asm volatile("s_waitcnt vmcnt(6)" ::: "memory");
        else                            asm volatile("s_waitcnt vmcnt(5)" ::: "memory");
      }
      __builtin_amdgcn_s_barrier();
    }
  }

  // ---------------- epilogue ----------------
  const size_t cb = (size_t)z * bsC;
  if constexpr (EPI == 6) {
    // P = exp(s*scale), store bf16; row-sum L via shfl-reduce + atomicAdd
    float* Lp = Lbuf + (size_t)z * 4096;
#pragma unroll
    for (int mf = 0; mf < 8; ++mf) {
#pragma unroll
      for (int r = 0; r < 4; ++r) {
        int gm = m0 + wm * 128 + mf * 16 + ((lid >> 4) << 2) + r;
        float rs = 0.0f;
#pragma unroll
        for (int nf = 0; nf < FN; ++nf) {
          int gn = n0 + wn * WN + nf * 16 + (lid & 15);
          float p = __expf(acc[mf][nf][r] * scale);
          u16 pb = f2bf(p);
          rs += bf2f(pb);               // sum what PV will actually consume
          C[cb + (size_t)gm * N + gn] = pb;
        }
        rs += __shfl_xor(rs, 1); rs += __shfl_xor(rs, 2);
        rs += __shfl_xor(rs, 4); rs += __shfl_xor(rs, 8);
        if ((lid & 15) == 0) atomicAdd(&Lp[gm], rs);
      }
    }
  } else if constexpr (EPI == 7) {
    const float* Lp = Lbuf + (size_t)z * 4096;
#pragma unroll
    for (int mf = 0; mf < 8; ++mf) {
#pragma unroll
      for (int r = 0; r < 4; ++r) {
        int gm = m0 + wm * 128 + mf * 16 + ((lid >> 4) << 2) + r;
        float inv = 1.0f / Lp[gm];
#pragma unroll
        for (int nf = 0; nf < FN; ++nf) {
          int gn = n0 + wn * WN + nf * 16 + (lid & 15);
          C[cb + (size_t)(gm >> 3) * 4096 + (size_t)(gm & 7) * 512 + gn] =
              f2bf(acc[mf][nf][r] * inv);
        }
      }
    }
  } else {
#pragma unroll
    for (int mf = 0; mf < 8; ++mf)
#pragma unroll
      for (int nf = 0; nf < FN; ++nf)
#pragma unroll
        for (int r = 0; r < 4; ++r) {
          int gm = m0 + wm * 128 + mf * 16 + ((lid >> 4) << 2) + r;
          int gn = n0 + wn * WN + nf * 16 + (lid & 15);
          float v = acc[mf][nf][r];
          if constexpr (EPI == 3) {
            C[cb + (size_t)gm * N + gn] = f2bf(v * scale);
          } else {
            C[cb + (size_t)(gm >> 3) * 4096 + (size_t)(gm & 7) * 512 + gn] = f2bf(v);
          }
        }
  }
}

// ---------------- generic B^T GEMM (projections / final), 128-tile ----------------
template<int BM, int BN, int EPI>
__global__ __launch_bounds__(256) void gemm_bt(
    const u16* __restrict__ A, const u16* __restrict__ B, void* __restrict__ Cv,
    const float* __restrict__ bias, int M, int N, int K, float scale,
    long bsA, long bsB, long bsC)
{
  constexpr int BK  = 64;
  constexpr int WMT = BM / 2, WNT = BN / 2;
  constexpr int FM  = BM / 32, FN = BN / 32;
  constexpr int STAGE = (BM + BN) * BK * 2;
  constexpr int EPIB  = (EPI == 2) ? BM * (BN + 1) * 2 : 0;
  __shared__ alignas(16) char smem[(STAGE > EPIB) ? STAGE : EPIB];
  u16* As = (u16*)smem;
  u16* Bs = As + BM * BK;

  const int tid = threadIdx.x;
  const int lid = tid & 63, wid = tid >> 6;
  const int m0 = blockIdx.y * BM, n0 = blockIdx.x * BN;
  const int z  = blockIdx.z;
  A += (size_t)z * bsA;
  B += (size_t)z * bsB;
  (void)M;

  const int wm = wid >> 1, wn = wid & 1;

  f32x4 acc[FM][FN];
#pragma unroll
  for (int i = 0; i < FM; ++i)
#pragma unroll
    for (int j = 0; j < FN; ++j) acc[i][j] = 0.0f;

  const int rA = lid >> 3;
  const int ke = (lid & 7) * 8;

  const int nK = K / BK;
  for (int kt = 0; kt < nK; ++kt) {
    const int k0 = kt * BK;
#pragma unroll
    for (int c = 0; c < BM / 32; ++c) {
      int chunk = wid * (BM / 32) + c;
      const u16* src = A + (size_t)(m0 + chunk * 8 + rA) * K + k0 + ke;
      gld_lds16(src, (char*)As + chunk * 1024);
    }
#pragma unroll
    for (int c = 0; c < BN / 32; ++c) {
      int chunk = wid * (BN / 32) + c;
      const u16* src = B + (size_t)(n0 + chunk * 8 + rA) * K + k0 + ke;
      gld_lds16(src, (char*)Bs + chunk * 1024);
    }
    __syncthreads();

#pragma unroll
    for (int kc = 0; kc < 2; ++kc) {
      bf16x8 af[FM], bfv[FN];
      const int kb = kc * 32 + (lid >> 4) * 8;
#pragma unroll
      for (int i = 0; i < FM; ++i)
        af[i] = *(const bf16x8*)&As[(wm * WMT + i * 16 + (lid & 15)) * BK + kb];
#pragma unroll
      for (int j = 0; j < FN; ++j)
        bfv[j] = *(const bf16x8*)&Bs[(wn * WNT + j * 16 + (lid & 15)) * BK + kb];
#pragma unroll
      for (int i = 0; i < FM; ++i)
#pragma unroll
        for (int j = 0; j < FN; ++j)
          acc[i][j] = __builtin_amdgcn_mfma_f32_16x16x32_bf16(af[i], bfv[j], acc[i][j], 0, 0, 0);
    }
    __syncthreads();
  }

#pragma unroll
  for (int i = 0; i < FM; ++i) {
#pragma unroll
    for (int j = 0; j < FN; ++j) {
#pragma unroll
      for (int r = 0; r < 4; ++r) {
        int lm = wm * WMT + i * 16 + ((lid >> 4) << 2) + r;
        int ln = wn * WNT + j * 16 + (lid & 15);
        int gm = m0 + lm, gn = n0 + ln;
        float val = acc[i][j][r];
        if constexpr (EPI == 0 || EPI == 1 || EPI == 2) val += bias[gn];
        if constexpr (EPI == 3) val *= scale;

        if constexpr (EPI == 0) {
          int b = gm >> 9, s = gm & 511, hh = gn >> 9, d2 = gn & 511;
          ((u16*)Cv)[(size_t)b * 2097152 + (size_t)((s << 3) + hh) * 512 + d2] = f2bf(val);
        } else if constexpr (EPI == 1) {
          int b = gm >> 9, s = gm & 511, hh = gn >> 9, d2 = gn & 511;
          ((u16*)Cv)[(size_t)b * 2097152 + (size_t)((hh << 9) + s) * 512 + d2] = f2bf(val);
        } else if constexpr (EPI == 2) {
          u16* E = (u16*)smem;
          E[lm * (BN + 1) + ln] = f2bf(val);
        } else if constexpr (EPI == 3) {
          u16* C = (u16*)Cv + (size_t)z * bsC;
          C[(size_t)gm * N + gn] = f2bf(val);
        } else if constexpr (EPI == 4) {
          u16* C = (u16*)Cv + (size_t)z * bsC;
          C[(size_t)(gm >> 3) * 4096 + (size_t)(gm & 7) * 512 + gn] = f2bf(val);
        } else {
          float* C = (float*)Cv;
          C[(size_t)gm * N + gn] = val + bias[gn];
        }
      }
    }
  }

  if constexpr (EPI == 2) {
    static_assert(BM == 128 && BN == 128, "V-proj epilogue assumes 128x128 tile");
    __syncthreads();
    int b = m0 >> 9, s0 = m0 & 511, hh = n0 >> 9, d20 = n0 & 511;
    u16* E = (u16*)smem;
    int c  = tid >> 1;
    int r0 = (tid & 1) * 64;
    u16* dst = (u16*)Cv + (size_t)b * 2097152 + (size_t)(d20 + c) * 4096 + (hh << 9) + s0 + r0;
#pragma unroll
    for (int i = 0; i < 64; i += 8) {
      u16x8 p;
#pragma unroll
      for (int jj = 0; jj < 8; ++jj) p[jj] = E[(r0 + i + jj) * (BN + 1) + c];
      *(u16x8*)(dst + i) = p;
    }
  }
}

// ---------------- row softmax over 4096 bf16, in place (fallback only) ----------------
__global__ __launch_bounds__(256) void softmax_kernel(u16* __restrict__ S) {
  const size_t row = blockIdx.x;
  u16* p = S + row * 4096;
  const int t = threadIdx.x;
  float v[16];
#pragma unroll
  for (int i = 0; i < 2; ++i) {
    u16x8 x = *(const u16x8*)(p + i * 2048 + t * 8);
#pragma unroll
    for (int j = 0; j < 8; ++j) v[i * 8 + j] = bf2f(x[j]);
  }
  float m = v[0];
#pragma unroll
  for (int i = 1; i < 16; ++i) m = fmaxf(m, v[i]);
#pragma unroll
  for (int o = 32; o; o >>= 1) m = fmaxf(m, __shfl_xor(m, o));
  __shared__ float red[8];
  int w = t >> 6;
  if ((t & 63) == 0) red[w] = m;
  __syncthreads();
  m = fmaxf(fmaxf(red[0], red[1]), fmaxf(red[2], red[3]));
  float sum = 0.0f;
#pragma unroll
  for (int i = 0; i < 16; ++i) { v[i] = __expf(v[i] - m); sum += v[i]; }
#pragma unroll
  for (int o = 32; o; o >>= 1) sum += __shfl_xor(sum, o);
  __syncthreads();
  if ((t & 63) == 0) red[4 + w] = sum;
  __syncthreads();
  sum = red[4] + red[5] + red[6] + red[7];
  float inv = 1.0f / sum;
#pragma unroll
  for (int i = 0; i < 2; ++i) {
    u16x8 x;
#pragma unroll
    for (int j = 0; j < 8; ++j) x[j] = f2bf(v[i * 8 + j] * inv);
    *(u16x8*)(p + i * 2048 + t * 8) = x;
  }
}

// ---------------------------------------------------------------------------
extern "C" void kernel_launch(void* const* d_in, const int* in_sizes, int n_in,
                              void* d_out, int out_size, void* d_ws, size_t ws_size,
                              hipStream_t stream) {
  (void)in_sizes; (void)n_in; (void)out_size;
  const float* q_f  = (const float*)d_in[0];
  const float* k_f  = (const float*)d_in[1];
  const float* v_f  = (const float*)d_in[2];
  const float* wq_b = (const float*)d_in[4];
  const float* wk_b = (const float*)d_in[6];
  const float* wv_b = (const float*)d_in[8];
  const float* ou_b = (const float*)d_in[10];
  float* out = (float*)d_out;

  char* ws = (char*)d_ws;
  u16* q_bf  = (u16*)(ws + 0);
  u16* k_bf  = (u16*)(ws + 2097152);
  u16* v_bf  = (u16*)(ws + 4194304);
  u16* wA_q  = (u16*)(ws + 6291456);    // bf16(wk_w)  (reference swaps wk<->wq)
  u16* wA_k  = (u16*)(ws + 10485760);   // bf16(wq_w)
  u16* wA_v  = (u16*)(ws + 14680064);   // bf16(wv_w)
  u16* ow_bf = (u16*)(ws + 18874368);   // bf16(out_w)
  u16* qp    = (u16*)(ws + 23068672);   // (4, 4096, 512) bf16, l = s*8+h
  u16* kp    = (u16*)(ws + 39845888);   // (4, 4096, 512) bf16, l' = h*512+s
  u16* vpt   = (u16*)(ws + 56623104);   // (4, 512, 4096) bf16, [d2][l']
  u16* oflat = (u16*)(ws + 73400320);   // (4, 512, 4096) bf16 (= o reshaped)
  u16* sc    = (u16*)(ws + 90177536);   // P = exp(scores*scl) bf16
  bool full = ws_size >= (size_t)90177536 + 134217728;

  // L row-sum buffer: first 64KB of d_out (dead until final GEMM overwrites it).
  float* L = (float*)d_out;

  // f32 -> bf16 converts
  cvt_kernel<<<512,  256, 0, stream>>>(q_f, q_bf, 1048576);
  cvt_kernel<<<512,  256, 0, stream>>>(k_f, k_bf, 1048576);
  cvt_kernel<<<512,  256, 0, stream>>>(v_f, v_bf, 1048576);
  cvt_kernel<<<1024, 256, 0, stream>>>((const float*)d_in[5], wA_q, 2097152);
  cvt_kernel<<<1024, 256, 0, stream>>>((const float*)d_in[3], wA_k, 2097152);
  cvt_kernel<<<1024, 256, 0, stream>>>((const float*)d_in[7], wA_v, 2097152);
  cvt_kernel<<<1024, 256, 0, stream>>>((const float*)d_in[9], ow_bf, 2097152);

  // projections (note reference swap: qp uses wk, kp uses wq)
  gemm_bt<128,128,0><<<dim3(32,16,1), 256, 0, stream>>>(q_bf, wA_q, qp,  wk_b, 2048,4096,512, 1.f, 0,0,0);
  gemm_bt<128,128,1><<<dim3(32,16,1), 256, 0, stream>>>(k_bf, wA_k, kp,  wq_b, 2048,4096,512, 1.f, 0,0,0);
  gemm_bt<128,128,2><<<dim3(32,16,1), 256, 0, stream>>>(v_bf, wA_v, vpt, wv_b, 2048,4096,512, 1.f, 0,0,0);

  const float scl = 0.04419417382415922f;  // 1/sqrt(512)
  if (full) {
    // zero L (graph-replay safe: done every launch, before scores atomics)
    hipMemsetAsync(L, 0, 65536, stream);
    // scores: P = exp(s*scl) + row-sums into L
    gemm8<256,6><<<dim3(16,16,4), 512, 0, stream>>>(qp, kp, sc, L, 4096, 512, scl,
                                                    2097152, 2097152, 16777216);
    // PV: O = (P @ V) / L
    gemm8<128,7><<<dim3(4,16,4), 512, 0, stream>>>(sc, vpt, oflat, L, 512, 4096, 1.f,
                                                   16777216, 2097152, 2097152);
  } else {
    for (int b = 0; b < 4; ++b) {
      gemm8<256,3><<<dim3(16,16,1), 512, 0, stream>>>(qp + b*2097152, kp + b*2097152, sc, nullptr,
                                                      4096, 512, scl, 0,0,0);
      softmax_kernel<<<4096, 256, 0, stream>>>(sc);
      gemm8<128,4><<<dim3(4,16,1), 512, 0, stream>>>(sc, vpt + b*2097152, oflat + b*2097152, nullptr,
                                                     512, 4096, 1.f, 0,0,0);
    }
  }
  // final projection, f32 output
  gemm_bt<64,64,5><<<dim3(8,32,1), 256, 0, stream>>>(oflat, ow_bf, out, ou_b, 2048,512,4096, 1.f, 0,0,0);
}